// Round 6
// baseline (526.732 us; speedup 1.0000x reference)
//
#include <hip/hip_runtime.h>
#include <math.h>

// Problem constants
#define BATCH  128
#define NIN    1152
#define DIN    8
#define NOUTC  10
#define DOUT   16
#define H1DIM  512
#define H2DIM  1024
#define PIX    784
#define NROWS  (BATCH * NOUTC)   // 1280
#define NBY3   13                // ceil(784/64) col-tiles in gemm3

typedef __attribute__((ext_vector_type(8))) __bf16 bf16x8;
typedef __attribute__((ext_vector_type(4))) float  f32x4;
typedef __attribute__((ext_vector_type(4))) unsigned int u32x4;

__device__ __forceinline__ float bf2f(unsigned int u) {
    union { unsigned int i; float f; } v; v.i = u << 16; return v.f;
}
__device__ __forceinline__ ushort f2bf(float f) {
    union { float f; unsigned int i; } v; v.f = f;
    unsigned int r = v.i + 0x7FFFu + ((v.i >> 16) & 1u);
    return (ushort)(r >> 16);
}
__device__ __forceinline__ float ldin(const void* p, size_t i, int isbf) {
    return isbf ? bf2f(((const ushort*)p)[i]) : ((const float*)p)[i];
}
__device__ __forceinline__ bf16x8 frag_of(uint4 u) {
    return __builtin_bit_cast(bf16x8, u);
}
__device__ __forceinline__ bf16x8 ld_frag(const ushort* p) {
    return frag_of(*(const uint4*)p);
}
// unpack a uint4 of 8 bf16 into 8 f32
__device__ __forceinline__ void unpack8(uint4 u, float* f) {
    f[0] = bf2f(u.x & 0xffffu); f[1] = bf2f(u.x >> 16);
    f[2] = bf2f(u.y & 0xffffu); f[3] = bf2f(u.y >> 16);
    f[4] = bf2f(u.z & 0xffffu); f[5] = bf2f(u.z >> 16);
    f[6] = bf2f(u.w & 0xffffu); f[7] = bf2f(u.w >> 16);
}

// per-block dtype detect: 1 KB of w, same answer in every block
__device__ __forceinline__ int detect_bf(const void* w, int* cntS) {
    int tid = threadIdx.x, nt = blockDim.x;
    if (tid == 0) *cntS = 0;
    __syncthreads();
    const ushort* u = (const ushort*)w;
    int c = 0;
    for (int s = tid; s < 512; s += nt) {
        int e = (u[s * 2] >> 7) & 0xFF;
        if (e >= 88 && e <= 140) c++;
    }
    atomicAdd(cntS, c);
    __syncthreads();
    return (*cntS >= 384) ? 1 : 0;
}

// ---------------------------------------------------------------------------
// prep args. segments: 0:W1 1:b1 2:b2 3:b3 4:x 5:W2^T 6:W3^T.
// ---------------------------------------------------------------------------
struct PrepArgs {
    const void* w;
    const void* src[7];
    ushort*     dst[7];
    int         n[7];
    int*        flag;
    int*        sync;    // 128 ints zeroed for the fused dispatches
};

// fallback-only (ws too small for hatG): original standalone prep
__global__ __launch_bounds__(256) void prep_kernel(PrepArgs a)
{
    __shared__ int cntS;
    __shared__ ushort tile[32][33];
    int tid = threadIdx.x;
    int isbf = detect_bf(a.w, &cntS);
    int seg = blockIdx.y;
    if (seg == 0 && blockIdx.x == 0 && tid == 0) *a.flag = isbf;

    if (seg <= 4) {
        int n = a.n[seg];
        int stride = gridDim.x * 256;
        ushort* d = a.dst[seg];
        if (isbf) {
            const ushort* s = (const ushort*)a.src[seg];
            for (int i = blockIdx.x * 256 + tid; i < n; i += stride) d[i] = s[i];
        } else {
            const float* s = (const float*)a.src[seg];
            for (int i = blockIdx.x * 256 + tid; i < n; i += stride) d[i] = f2bf(s[i]);
        }
        return;
    }
    int R = (seg == 5) ? H1DIM : H2DIM;
    int C = (seg == 5) ? H2DIM : PIX;
    int tilesX = (seg == 5) ? 32 : 25;
    int tilesY = (seg == 5) ? 16 : 32;
    int t = blockIdx.x;
    if (t >= tilesX * tilesY) return;
    int tx2 = t % tilesX, ty2 = t / tilesX;
    int c0 = tx2 * 32, r0 = ty2 * 32;
    const void* in = a.src[seg];
    ushort* out = a.dst[seg];
    int tx = tid & 31, ty = tid >> 5;
    for (int i = ty; i < 32; i += 8) {
        int r = r0 + i, c = c0 + tx;
        tile[i][tx] = (r < R && c < C) ? f2bf(ldin(in, (size_t)r * C + c, isbf)) : (ushort)0;
    }
    __syncthreads();
    for (int i = ty; i < 32; i += 8) {
        int c = c0 + i, r = r0 + tx;
        if (c < C && r < R) out[(size_t)c * R + r] = tile[tx][i];
    }
}

// ---------------------------------------------------------------------------
// hat_prep_kernel: merged hat_build + prep (round-2 structure, verified).
// Also zeroes the fused-dispatch sync counters (p==0 block).
// ---------------------------------------------------------------------------
__global__ __launch_bounds__(256) void hat_prep_kernel(
    const void* __restrict__ inc,
    PrepArgs a,
    ushort* __restrict__ hatG)
{
    __shared__ int cntS;
    __shared__ ushort tile[32][33];
    int tid = threadIdx.x;
    int isbf = detect_bf(a.w, &cntS);

    if (blockIdx.z >= NOUTC) {
        int p = (blockIdx.z - NOUTC) * 144 + blockIdx.y * 9 + blockIdx.x;  // 0..575
        if (p == 0) {
            if (tid == 0) *a.flag = isbf;
            if (tid < 128) a.sync[tid] = 0;
        }
        if (p < 528) {
            for (int t = p; t < 1312; t += 528) {
                int seg = (t < 512) ? 5 : 6;
                int tt  = (seg == 5) ? t : t - 512;
                int R = (seg == 5) ? H1DIM : H2DIM;
                int C = (seg == 5) ? H2DIM : PIX;
                int tilesX = (seg == 5) ? 32 : 25;
                int tx2 = tt % tilesX, ty2 = tt / tilesX;
                int c0 = tx2 * 32, r0 = ty2 * 32;
                const void* in = a.src[seg];
                ushort* out = a.dst[seg];
                int tx = tid & 31, ty = tid >> 5;
                for (int i = ty; i < 32; i += 8) {
                    int r = r0 + i, c = c0 + tx;
                    tile[i][tx] = (r < R && c < C) ? f2bf(ldin(in, (size_t)r * C + c, isbf)) : (ushort)0;
                }
                __syncthreads();
                for (int i = ty; i < 32; i += 8) {
                    int c = c0 + i, r = r0 + tx;
                    if (c < C && r < R) out[(size_t)c * R + r] = tile[tx][i];
                }
                __syncthreads();
            }
        } else {
            int base = (p - 528) * 256 + tid;
            const int stride = 48 * 256;
            #pragma unroll
            for (int seg = 0; seg <= 4; seg++) {
                int n = a.n[seg];
                ushort* d = a.dst[seg];
                if (isbf) {
                    const ushort* s = (const ushort*)a.src[seg];
                    for (int i = base; i < n; i += stride) d[i] = s[i];
                } else {
                    const float* s = (const float*)a.src[seg];
                    for (int i = base; i < n; i += stride) d[i] = f2bf(s[i]);
                }
            }
        }
        return;
    }

    // -------- hat path: 8 batches per block, all loads in prologue --------
    int kc = blockIdx.x, bc = blockIdx.y, n = blockIdx.z;
    int k  = kc * 128 + (tid >> 1);
    int oh = (tid & 1) << 3;
    int b0 = bc * 8;

    size_t wbase = ((size_t)n * NIN + k) * DOUT + oh;

    if (isbf) {
        uint4 wr[8], ir[8];
        const uint4* wp = (const uint4*)((const ushort*)a.w + wbase * DIN);
        const ushort* ip = (const ushort*)inc;
        #pragma unroll
        for (int j = 0; j < 8; j++) wr[j] = wp[j];
        #pragma unroll
        for (int bl = 0; bl < 8; bl++)
            ir[bl] = *(const uint4*)(ip + ((size_t)(b0 + bl) * NIN + k) * DIN);
        float wf[8][8];
        #pragma unroll
        for (int j = 0; j < 8; j++) unpack8(wr[j], wf[j]);
        #pragma unroll
        for (int bl = 0; bl < 8; bl++) {
            float xi[8];
            unpack8(ir[bl], xi);
            unsigned int hh[8];
            #pragma unroll
            for (int j = 0; j < 8; j++) {
                float s = wf[j][0] * xi[0] + wf[j][1] * xi[1] + wf[j][2] * xi[2] +
                          wf[j][3] * xi[3] + wf[j][4] * xi[4] + wf[j][5] * xi[5] +
                          wf[j][6] * xi[6] + wf[j][7] * xi[7];
                hh[j] = f2bf(s);
            }
            u32x4 ov = { hh[0] | (hh[1] << 16), hh[2] | (hh[3] << 16),
                         hh[4] | (hh[5] << 16), hh[6] | (hh[7] << 16) };
            *(u32x4*)(hatG + (((size_t)((b0 + bl) * NOUTC + n) * NIN + k) * DOUT + oh)) = ov;
        }
    } else {
        float4 wlo[8], whi[8], ilo[8], ihi[8];
        const float4* wp = (const float4*)((const float*)a.w + wbase * DIN);
        const float*  ip = (const float*)inc;
        #pragma unroll
        for (int j = 0; j < 8; j++) { wlo[j] = wp[2 * j]; whi[j] = wp[2 * j + 1]; }
        #pragma unroll
        for (int bl = 0; bl < 8; bl++) {
            const float4* q = (const float4*)(ip + ((size_t)(b0 + bl) * NIN + k) * DIN);
            ilo[bl] = q[0]; ihi[bl] = q[1];
        }
        #pragma unroll
        for (int bl = 0; bl < 8; bl++) {
            float4 lo = ilo[bl], hi = ihi[bl];
            unsigned int hh[8];
            #pragma unroll
            for (int j = 0; j < 8; j++) {
                float s = wlo[j].x * lo.x + wlo[j].y * lo.y + wlo[j].z * lo.z +
                          wlo[j].w * lo.w + whi[j].x * hi.x + whi[j].y * hi.y +
                          whi[j].z * hi.z + whi[j].w * hi.w;
                hh[j] = f2bf(s);
            }
            u32x4 ov = { hh[0] | (hh[1] << 16), hh[2] | (hh[3] << 16),
                         hh[4] | (hh[5] << 16), hh[6] | (hh[7] << 16) };
            *(u32x4*)(hatG + (((size_t)((b0 + bl) * NOUTC + n) * NIN + k) * DOUT + oh)) = ov;
        }
    }
}

// ---------------------------------------------------------------------------
// Shared plumbing for the fused pipeline
// ---------------------------------------------------------------------------
struct MegaArgs {
    const ushort* hatG;
    const ushort* W1c; const ushort* b1c;
    const ushort* W2T; const ushort* b2c;
    const ushort* W3T; const ushort* b3c;
    const ushort* xc;
    ushort* h1; ushort* h2;
    ushort* bsA; ushort* bsB;
    float*  partials;
    void*   outFinal;
    const int* flagp;
};

union MegaSmem {                      // 20 KB exactly (gemm view dominates)
    struct { uint4 As4[640]; uint4 Bs4[640]; } g;
    struct { ushort wSb[NIN]; float redS[4][16]; float sumS[16];
             float ocS[16]; float scaleS; } r;
};

// 256-thread reduce item: thread t owns FULL hat rows t+256j + tail row.
__device__ __forceinline__ void red_item(
    const MegaArgs& A, MegaSmem& S, int bn, int notFirst,
    const ushort* bsPrev, ushort* bsOut, ushort* h1out, int writeOut)
{
    int n = bn % NOUTC, b = bn / NOUTC;
    int t = threadIdx.x;
    int wave = t >> 6, lane = t & 63;
    const ushort* hbase = A.hatG + (size_t)bn * NIN * DOUT;

    uint4 v[4][2];
    #pragma unroll
    for (int j = 0; j < 4; j++) {
        v[j][0] = *(const uint4*)(hbase + (t + 256 * j) * DOUT);
        v[j][1] = *(const uint4*)(hbase + (t + 256 * j) * DOUT + 8);
    }
    uint4 vt0 = make_uint4(0,0,0,0), vt1 = make_uint4(0,0,0,0);
    if (t < 128) {
        vt0 = *(const uint4*)(hbase + (1024 + t) * DOUT);
        vt1 = *(const uint4*)(hbase + (1024 + t) * DOUT + 8);
    }

    if (notFirst) {
        if (t < 9) {
            float s = 0.f;
            #pragma unroll
            for (int j = 0; j < NBY3; j++)
                s += A.partials[(size_t)(b * NOUTC + t) * 16 + j];
            S.r.sumS[t] = -s;
        }
        __syncthreads();
        float mn = 1e30f, mx = -1e30f;
        #pragma unroll
        for (int n2 = 0; n2 < 9; n2++) {
            float vv = S.r.sumS[n2];
            mn = fminf(mn, vv); mx = fmaxf(mx, vv);
        }
        float den = fmaxf(mx - mn, 1e-6f);
        float rv = (n < 9) ? fmaxf((S.r.sumS[n] - mn) / den, 0.5f) : 0.5f;
        __syncthreads();
        for (int k = t; k < NIN; k += 256) {
            float c = 0.5f;
            if (n < 9) {
                float vv[9], mn2 = 1e30f, mx2 = -1e30f;
                #pragma unroll
                for (int n2 = 0; n2 < 9; n2++) {
                    vv[n2] = bf2f(bsPrev[(size_t)(b * NOUTC + n2) * NIN + k]);
                    mn2 = fminf(mn2, vv[n2]); mx2 = fmaxf(mx2, vv[n2]);
                }
                float den2 = fmaxf(mx2 - mn2, 1e-6f);
                c = fmaxf((vv[n] - mn2) / den2, 0.5f);
            }
            S.r.wSb[k] = f2bf(c * rv);
        }
    }
    __syncthreads();

    float acc[16];
    #pragma unroll
    for (int o = 0; o < 16; o++) acc[o] = 0.f;
    #pragma unroll
    for (int j = 0; j < 4; j++) {
        int k = t + 256 * j;
        float w = notFirst ? bf2f(S.r.wSb[k]) : 1.f;
        bf16x8 h0 = frag_of(v[j][0]), h1v = frag_of(v[j][1]);
        #pragma unroll
        for (int o = 0; o < 8; o++) {
            acc[o]     += w * (float)h0[o];
            acc[8 + o] += w * (float)h1v[o];
        }
    }
    if (t < 128) {
        float w = notFirst ? bf2f(S.r.wSb[1024 + t]) : 1.f;
        bf16x8 h0 = frag_of(vt0), h1v = frag_of(vt1);
        #pragma unroll
        for (int o = 0; o < 8; o++) {
            acc[o]     += w * (float)h0[o];
            acc[8 + o] += w * (float)h1v[o];
        }
    }
    #pragma unroll
    for (int off = 32; off >= 1; off >>= 1) {
        #pragma unroll
        for (int o = 0; o < 16; o++) acc[o] += __shfl_xor(acc[o], off);
    }
    if (lane == 0) {
        #pragma unroll
        for (int o = 0; o < 16; o++) S.r.redS[wave][o] = acc[o];
    }
    __syncthreads();
    if (t < 16) {
        float s = 0.f;
        #pragma unroll
        for (int wv = 0; wv < 4; wv++) s += S.r.redS[wv][t];
        S.r.sumS[t] = s;
    }
    __syncthreads();
    if (t == 0) {
        float n2 = 0.f;
        #pragma unroll
        for (int o = 0; o < 16; o++) n2 += S.r.sumS[o] * S.r.sumS[o];
        float nrm = sqrtf(n2);
        S.r.scaleS = n2 / (1.f + n2) / (nrm + 1e-8f);
    }
    __syncthreads();
    if (t < 16) {
        float oc = S.r.scaleS * S.r.sumS[t];
        S.r.ocS[t] = oc;
        if (writeOut) {
            if (*A.flagp) ((ushort*)A.outFinal)[(size_t)bn * 16 + t] = f2bf(oc);
            else          ((float*) A.outFinal)[(size_t)bn * 16 + t] = oc;
        }
    }
    __syncthreads();

    if (bsOut) {
        float oc[16];
        #pragma unroll
        for (int o = 0; o < 16; o++) oc[o] = S.r.ocS[o];
        #pragma unroll
        for (int j = 0; j < 4; j++) {
            bf16x8 h0 = frag_of(v[j][0]), h1v = frag_of(v[j][1]);
            float s = 0.f;
            #pragma unroll
            for (int o = 0; o < 8; o++)
                s += oc[o] * (float)h0[o] + oc[8 + o] * (float)h1v[o];
            bsOut[(size_t)bn * NIN + t + 256 * j] = f2bf(s);
        }
        if (t < 128) {
            bf16x8 h0 = frag_of(vt0), h1v = frag_of(vt1);
            float s = 0.f;
            #pragma unroll
            for (int o = 0; o < 8; o++)
                s += oc[o] * (float)h0[o] + oc[8 + o] * (float)h1v[o];
            bsOut[(size_t)bn * NIN + 1024 + t] = f2bf(s);
        }
    }
    if (h1out) {
        #pragma unroll
        for (int cc = 0; cc < 2; cc++) {
            int col = t + 256 * cc;
            float acc1 = bf2f(A.b1c[col]);
            #pragma unroll
            for (int i = 0; i < 16; i++)
                acc1 += S.r.ocS[i] * bf2f(A.W1c[(size_t)(n * 16 + i) * H1DIM + col]);
            h1out[(size_t)bn * H1DIM + col] = f2bf(fmaxf(acc1, 0.f));
        }
    }
}

// 64x64 MFMA GEMM tile (64-wide k-stages, LDS rows padded to 40 ushorts)
__device__ __forceinline__ void gemm_tile(
    MegaSmem& S, const ushort* __restrict__ A_, const ushort* __restrict__ Bt,
    const ushort* __restrict__ bias, int K, int N,
    ushort* __restrict__ Cout, const ushort* __restrict__ xin,
    float* __restrict__ partials, int m0, int n0, int tileY)
{
    int tid = threadIdx.x;
    int wave = tid >> 6, lane = tid & 63, quad = lane >> 4, l16 = lane & 15;
    uint4* As4 = S.g.As4;
    uint4* Bs4 = S.g.Bs4;
    ushort* As = (ushort*)As4;
    ushort* Bs = (ushort*)Bs4;

    f32x4 acc[4];
    #pragma unroll
    for (int nt = 0; nt < 4; nt++)
        #pragma unroll
        for (int rg = 0; rg < 4; rg++) acc[nt][rg] = 0.f;

    int sMi = tid >> 2, sKk = (tid & 3) * 8;
    int sLds = sMi * 5 + (tid & 3);
    const ushort* Ap = A_ + (size_t)(m0 + sMi) * K + sKk;
    const ushort* Bp = Bt + (size_t)(n0 + sMi) * K + sKk;
    bool bOK = (n0 + sMi) < N;

    uint4 aR0 = *(const uint4*)Ap;
    uint4 aR1 = *(const uint4*)(Ap + 32);
    uint4 bR0 = bOK ? *(const uint4*)Bp : make_uint4(0, 0, 0, 0);
    uint4 bR1 = bOK ? *(const uint4*)(Bp + 32) : make_uint4(0, 0, 0, 0);

    for (int k0 = 0; k0 < K; k0 += 64) {
        As4[sLds]       = aR0;
        As4[320 + sLds] = aR1;
        Bs4[sLds]       = bR0;
        Bs4[320 + sLds] = bR1;
        __syncthreads();
        if (k0 + 64 < K) {
            aR0 = *(const uint4*)(Ap + k0 + 64);
            aR1 = *(const uint4*)(Ap + k0 + 96);
            bR0 = bOK ? *(const uint4*)(Bp + k0 + 64) : make_uint4(0, 0, 0, 0);
            bR1 = bOK ? *(const uint4*)(Bp + k0 + 96) : make_uint4(0, 0, 0, 0);
        }
        #pragma unroll
        for (int c = 0; c < 2; c++) {
            bf16x8 a = ld_frag(As + c * 2560 + (wave * 16 + l16) * 40 + quad * 8);
            #pragma unroll
            for (int nt = 0; nt < 4; nt++) {
                bf16x8 bb = ld_frag(Bs + c * 2560 + (nt * 16 + l16) * 40 + quad * 8);
                acc[nt] = __builtin_amdgcn_mfma_f32_16x16x32_bf16(a, bb, acc[nt], 0, 0, 0);
            }
        }
        __syncthreads();
    }

    int rowBase = m0 + wave * 16 + quad * 4;
    if (Cout) {
        #pragma unroll
        for (int nt = 0; nt < 4; nt++) {
            int col = n0 + nt * 16 + l16;
            float bv = bf2f(bias[col]);
            #pragma unroll
            for (int rg = 0; rg < 4; rg++) {
                float v = acc[nt][rg] + bv;
                Cout[(size_t)(rowBase + rg) * N + col] = f2bf(fmaxf(v, 0.f));
            }
        }
    } else {
        float vr[4] = {0.f, 0.f, 0.f, 0.f};
        #pragma unroll
        for (int nt = 0; nt < 4; nt++) {
            int col = n0 + nt * 16 + l16;
            if (col < N) {
                float bv = bf2f(bias[col]);
                #pragma unroll
                for (int rg = 0; rg < 4; rg++) {
                    int row = rowBase + rg;
                    int bb = row / NOUTC;
                    float z = acc[nt][rg] + bv;
                    float s = 1.f / (1.f + __expf(-z));
                    float d = bf2f(xin[(size_t)bb * PIX + col]) - s;
                    vr[rg] += d * d;
                }
            }
        }
        #pragma unroll
        for (int rg = 0; rg < 4; rg++) {
            float v = vr[rg];
            #pragma unroll
            for (int off = 8; off >= 1; off >>= 1) v += __shfl_xor(v, off, 16);
            if (l16 == 0)
                partials[(size_t)(rowBase + rg) * 16 + tileY] = v;
        }
    }
}

// release: all block stores visible device-wide, then bump counter
__device__ __forceinline__ void signal_cnt(int* cnt) {
    __syncthreads();
    if (threadIdx.x == 0) { __threadfence(); atomicAdd(cnt, 1); }
}
// acquire: wait counter, invalidate caches, release block
__device__ __forceinline__ void wait_cnt(int* cnt, int target) {
    if (threadIdx.x == 0) {
        while (atomicAdd(cnt, 0) < target) __builtin_amdgcn_s_sleep(1);
        __threadfence();
    }
    __syncthreads();
}

// ---------------------------------------------------------------------------
// fused_iter: one dispatch = {red items, g1, g3} with intra-dispatch
// producer-consumer sync. Grid MUST be 1024 blocks: __launch_bounds__(256,4)
// + 20KB LDS guarantee 4 blocks/CU x 256 CUs = all 1024 co-resident, so the
// spins are deadlock-free without relying on dispatch order.
//   blocks 0..319   : red item bid,        then g1 tile bid   (wait cnt1)
//   blocks 320..579 : red item bid,        then g3 tile bid-320 (wait cnt2)
//   blocks 580..835 : red items bid, 1024+(bid-580)
//   blocks 836..1023: red item bid
// redMode 0: iter0 (rc=1, bs->bsA); 1: mid (bsA->bsB). h1 written both.
// ---------------------------------------------------------------------------
__global__ __launch_bounds__(256, 4) void fused_iter(
    MegaArgs A, int* cnt1, int* cnt2, int redMode)
{
    __shared__ MegaSmem S;
    int bid = blockIdx.x;
    int tid = threadIdx.x;

    // ---- phase R: red items (depend only on previous dispatches) ----
    {
        int bn = bid;
        if (redMode == 0) red_item(A, S, bn, 0, nullptr, A.bsA, A.h1, 0);
        else              red_item(A, S, bn, 1, A.bsA, A.bsB, A.h1, 0);
        signal_cnt(&cnt1[bn >> 6]);
    }
    if (bid >= 580 && bid < 836) {
        int bn = 1024 + (bid - 580);
        __syncthreads();
        if (redMode == 0) red_item(A, S, bn, 0, nullptr, A.bsA, A.h1, 0);
        else              red_item(A, S, bn, 1, A.bsA, A.bsB, A.h1, 0);
        signal_cnt(&cnt1[bn >> 6]);
        return;
    }

    if (bid < 320) {
        // ---- g1 tile: h1 @ W2T -> h2 ----
        int m0 = bid % 20, n0v = bid / 20;
        wait_cnt(&cnt1[m0], 64);
        gemm_tile(S, A.h1, A.W2T, A.b2c, H1DIM, H2DIM, A.h2,
                  nullptr, nullptr, m0 * 64, n0v * 64, 0);
        signal_cnt(&cnt2[m0]);
    } else if (bid < 580) {
        // ---- g3 tile: h2 @ W3T -> partials ----
        int u = bid - 320;
        int m0 = u % 20, cy = u / 20;
        wait_cnt(&cnt2[m0], 16);
        gemm_tile(S, A.h2, A.W3T, A.b3c, H2DIM, PIX, nullptr,
                  A.xc, A.partials, m0 * 64, cy * 64, cy);
    }
}

// ---------------------------------------------------------------------------
// Standalone wrappers (final red pass + fallbacks)
// mode 0: iter0 (bs->bsA, h1); 1: mid (bsA->bsB, h1); 2: last (bsB->out)
// ---------------------------------------------------------------------------
__global__ __launch_bounds__(256) void red_pass256(MegaArgs A, int mode)
{
    __shared__ MegaSmem S;
    if (mode == 0)      red_item(A, S, blockIdx.x, 0, nullptr, A.bsA, A.h1, 0);
    else if (mode == 1) red_item(A, S, blockIdx.x, 1, A.bsA, A.bsB, A.h1, 0);
    else                red_item(A, S, blockIdx.x, 1, A.bsB, nullptr, nullptr, 1);
}

__global__ __launch_bounds__(256) void gemm_kernel(
    const ushort* __restrict__ A, const ushort* __restrict__ Bt,
    const ushort* __restrict__ bias, int K, int N,
    ushort* __restrict__ Cout,
    const ushort* __restrict__ xin, float* __restrict__ partials)
{
    __shared__ MegaSmem S;
    gemm_tile(S, A, Bt, bias, K, N, Cout, xin, partials,
              blockIdx.x * 64, blockIdx.y * 64, blockIdx.y);
}

// ---------------------------------------------------------------------------
// Fallback path (ws too small for hatG): 512-thread compute-reduce
// ---------------------------------------------------------------------------
__global__ __launch_bounds__(512, 4) void reduce_compute(
    const void*   __restrict__ incRaw,
    const void*   __restrict__ wRaw,
    const ushort* __restrict__ bsPrev,
    const float*  __restrict__ partials,
    int iter0,
    const ushort* __restrict__ W1c,
    const ushort* __restrict__ b1c,
    ushort* __restrict__ h1out,
    ushort* __restrict__ bsOut,
    void*   __restrict__ outFinal,
    const int* __restrict__ flagp)
{
    int bn  = blockIdx.x;
    int n   = bn % NOUTC;
    int b   = bn / NOUTC;
    int tid = threadIdx.x;

    __shared__ ushort wSb[NIN];
    __shared__ float  redS[8][16];
    __shared__ float  sumS[16];
    __shared__ float  ocS[16];
    __shared__ float  scaleS;

    int h = tid & 1, kb = tid >> 1;
    int wave = tid >> 6, lane = tid & 63;

    uint4 v[4];
    const ushort* tailS;

    __shared__ int cntS;
    __shared__ uint4 hatS4[NIN * DOUT / 8];
    int isbf = detect_bf(wRaw, &cntS);
    size_t wnb = (size_t)n * NIN * DOUT * DIN;
    for (int idx = tid; idx < NIN * DOUT; idx += 512) {
        int k = idx >> 4;
        float s = 0.f;
        #pragma unroll
        for (int i = 0; i < 8; i++)
            s += ldin(wRaw, wnb + (size_t)idx * 8 + i, isbf) *
                 ldin(incRaw, ((size_t)b * NIN + k) * DIN + i, isbf);
        ((ushort*)hatS4)[idx] = f2bf(s);
    }
    __syncthreads();
    const ushort* hbase = (const ushort*)hatS4;
    #pragma unroll
    for (int j = 0; j < 4; j++)
        v[j] = *(const uint4*)(hbase + ((kb + 256 * j) * DOUT + h * 8));
    tailS = hbase + 1024 * DOUT;

    if (!iter0) {
        if (tid < 9) {
            float s = 0.f;
            #pragma unroll
            for (int j = 0; j < NBY3; j++)
                s += partials[(size_t)(b * NOUTC + tid) * 16 + j];
            sumS[tid] = -s;
        }
        __syncthreads();
        float mn = 1e30f, mx = -1e30f;
        #pragma unroll
        for (int n2 = 0; n2 < 9; n2++) {
            float vv = sumS[n2];
            mn = fminf(mn, vv); mx = fmaxf(mx, vv);
        }
        float den = fmaxf(mx - mn, 1e-6f);
        float rv = (n < 9) ? fmaxf((sumS[n] - mn) / den, 0.5f) : 0.5f;
        for (int k = tid; k < NIN; k += 512) {
            float c = 0.5f;
            if (n < 9) {
                float vv[9], mn2 = 1e30f, mx2 = -1e30f;
                #pragma unroll
                for (int n2 = 0; n2 < 9; n2++) {
                    vv[n2] = bf2f(bsPrev[(size_t)(b * NOUTC + n2) * NIN + k]);
                    mn2 = fminf(mn2, vv[n2]); mx2 = fmaxf(mx2, vv[n2]);
                }
                float den2 = fmaxf(mx2 - mn2, 1e-6f);
                c = fmaxf((vv[n] - mn2) / den2, 0.5f);
            }
            wSb[k] = f2bf(c * rv);
        }
    }
    __syncthreads();

    float acc[8];
    #pragma unroll
    for (int o = 0; o < 8; o++) acc[o] = 0.f;
    #pragma unroll
    for (int j = 0; j < 4; j++) {
        int k = kb + 256 * j;
        float w = iter0 ? 1.f : bf2f(wSb[k]);
        bf16x8 hv = frag_of(v[j]);
        #pragma unroll
        for (int o = 0; o < 8; o++) acc[o] += w * (float)hv[o];
    }
    if (tid < 256) {
        int k = 1024 + kb;
        float w = iter0 ? 1.f : bf2f(wSb[k]);
        bf16x8 hv = ld_frag(tailS + kb * DOUT + h * 8);
        #pragma unroll
        for (int o = 0; o < 8; o++) acc[o] += w * (float)hv[o];
    }
    #pragma unroll
    for (int off = 32; off >= 2; off >>= 1) {
        #pragma unroll
        for (int o = 0; o < 8; o++) acc[o] += __shfl_xor(acc[o], off);
    }
    if (lane < 2) {
        #pragma unroll
        for (int o = 0; o < 8; o++) redS[wave][lane * 8 + o] = acc[o];
    }
    __syncthreads();
    if (tid < 16) {
        float s = 0.f;
        #pragma unroll
        for (int wv = 0; wv < 8; wv++) s += redS[wv][tid];
        sumS[tid] = s;
    }
    __syncthreads();
    if (tid == 0) {
        float n2 = 0.f;
        #pragma unroll
        for (int o = 0; o < 16; o++) n2 += sumS[o] * sumS[o];
        float nrm = sqrtf(n2);
        scaleS = n2 / (1.f + n2) / (nrm + 1e-8f);
    }
    __syncthreads();
    if (tid < 16) {
        float oc = scaleS * sumS[tid];
        ocS[tid] = oc;
        if (outFinal) {
            if (*flagp) ((ushort*)outFinal)[(size_t)bn * 16 + tid] = f2bf(oc);
            else        ((float*) outFinal)[(size_t)bn * 16 + tid] = oc;
        }
    }
    __syncthreads();

    if (bsOut) {
        float o0 = ocS[h * 8 + 0], o1 = ocS[h * 8 + 1], o2 = ocS[h * 8 + 2],
              o3 = ocS[h * 8 + 3], o4 = ocS[h * 8 + 4], o5 = ocS[h * 8 + 5],
              o6 = ocS[h * 8 + 6], o7 = ocS[h * 8 + 7];
        #pragma unroll
        for (int j = 0; j < 4; j++) {
            bf16x8 hv = frag_of(v[j]);
            float s = o0 * (float)hv[0] + o1 * (float)hv[1] + o2 * (float)hv[2] +
                      o3 * (float)hv[3] + o4 * (float)hv[4] + o5 * (float)hv[5] +
                      o6 * (float)hv[6] + o7 * (float)hv[7];
            s += __shfl_xor(s, 1);
            if (h == 0) bsOut[(size_t)bn * NIN + kb + 256 * j] = f2bf(s);
        }
        if (tid < 256) {
            bf16x8 hv = ld_frag(tailS + kb * DOUT + h * 8);
            float s = o0 * (float)hv[0] + o1 * (float)hv[1] + o2 * (float)hv[2] +
                      o3 * (float)hv[3] + o4 * (float)hv[4] + o5 * (float)hv[5] +
                      o6 * (float)hv[6] + o7 * (float)hv[7];
            s += __shfl_xor(s, 1);
            if (h == 0) bsOut[(size_t)bn * NIN + 1024 + kb] = f2bf(s);
        }
    }

    if (h1out) {
        int col = tid;
        float acc1 = bf2f(b1c[col]);
        #pragma unroll
        for (int i = 0; i < 16; i++)
            acc1 += ocS[i] * bf2f(W1c[(size_t)(n * 16 + i) * H1DIM + col]);
        h1out[(size_t)bn * H1DIM + col] = f2bf(fmaxf(acc1, 0.f));
    }
}

// ---------------------------------------------------------------------------
extern "C" void kernel_launch(void* const* d_in, const int* in_sizes, int n_in,
                              void* d_out, int out_size, void* d_ws, size_t ws_size,
                              hipStream_t stream)
{
    const void* inc = d_in[0];
    const void* x   = d_in[1];
    const void* w   = d_in[2];
    const void* W1  = d_in[3];
    const void* b1  = d_in[4];
    const void* W2  = d_in[5];
    const void* b2  = d_in[6];
    const void* W3  = d_in[7];
    const void* b3  = d_in[8];

    char* p = (char*)d_ws;
    auto alloc = [&](size_t bytes) { void* r = p; p += (bytes + 255) & ~(size_t)255; return r; };
    int*    flagWS    = (int*)alloc(256);
    int*    syncWS    = (int*)alloc(128 * sizeof(int));
    ushort* bsA       = (ushort*)alloc((size_t)NROWS * NIN * 2);
    ushort* bsB       = (ushort*)alloc((size_t)NROWS * NIN * 2);
    float*  partials  = (float*)alloc((size_t)NROWS * 16 * 4);
    ushort* h1WS      = (ushort*)alloc((size_t)NROWS * H1DIM * 2);
    ushort* h2WS      = (ushort*)alloc((size_t)NROWS * H2DIM * 2);
    ushort* W2T       = (ushort*)alloc((size_t)H2DIM * H1DIM * 2);
    ushort* W3T       = (ushort*)alloc((size_t)PIX * H2DIM * 2);
    ushort* W1c       = (ushort*)alloc((size_t)160 * H1DIM * 2);
    ushort* b1c       = (ushort*)alloc((size_t)H1DIM * 2);
    ushort* b2c       = (ushort*)alloc((size_t)H2DIM * 2);
    ushort* b3c       = (ushort*)alloc((size_t)PIX * 2);
    ushort* xc        = (ushort*)alloc((size_t)BATCH * PIX * 2);
    ushort* hatG      = (ushort*)alloc((size_t)NROWS * NIN * DOUT * 2);  // 47 MB, LAST
    bool haveHat = ((char*)hatG + (size_t)NROWS * NIN * DOUT * 2) <= ((char*)d_ws + ws_size);

    PrepArgs pa;
    pa.w = w;
    pa.src[0] = W1;  pa.dst[0] = W1c;  pa.n[0] = 160 * H1DIM;
    pa.src[1] = b1;  pa.dst[1] = b1c;  pa.n[1] = H1DIM;
    pa.src[2] = b2;  pa.dst[2] = b2c;  pa.n[2] = H2DIM;
    pa.src[3] = b3;  pa.dst[3] = b3c;  pa.n[3] = PIX;
    pa.src[4] = x;   pa.dst[4] = xc;   pa.n[4] = BATCH * PIX;
    pa.src[5] = W2;  pa.dst[5] = W2T;  pa.n[5] = 0;
    pa.src[6] = W3;  pa.dst[6] = W3T;  pa.n[6] = 0;
    pa.flag = flagWS;
    pa.sync = syncWS;

    if (!haveHat) {
        // ws too small: original separated compute path
        prep_kernel<<<dim3(800, 7), 256, 0, stream>>>(pa);
        reduce_compute<<<NROWS, 512, 0, stream>>>(
            inc, w, nullptr, nullptr, 1, W1c, b1c, h1WS, bsA, nullptr, flagWS);
        for (int it = 0; it < 2; it++) {
            gemm_kernel<<<dim3(NROWS / 64, H2DIM / 64), 256, 0, stream>>>(
                h1WS, W2T, b2c, H1DIM, H2DIM, h2WS, nullptr, nullptr);
            gemm_kernel<<<dim3(NROWS / 64, NBY3), 256, 0, stream>>>(
                h2WS, W3T, b3c, H2DIM, PIX, nullptr, xc, partials);
            int last = (it == 1);
            const ushort* bsP = (it == 0) ? bsA : bsB;
            ushort* bsO       = last ? nullptr : bsB;
            ushort* h1o       = last ? nullptr : h1WS;
            void*   fin       = last ? d_out : nullptr;
            reduce_compute<<<NROWS, 512, 0, stream>>>(
                inc, w, bsP, partials, 0, W1c, b1c, h1o, bsO, fin, flagWS);
        }
        return;
    }

    hat_prep_kernel<<<dim3(9, 16, NOUTC + 4), 256, 0, stream>>>(inc, pa, hatG);

    MegaArgs ma;
    ma.hatG = hatG; ma.W1c = W1c; ma.b1c = b1c;
    ma.W2T = W2T;   ma.b2c = b2c; ma.W3T = W3T; ma.b3c = b3c;
    ma.xc = xc;     ma.h1 = h1WS; ma.h2 = h2WS;
    ma.bsA = bsA;   ma.bsB = bsB; ma.partials = partials;
    ma.outFinal = d_out; ma.flagp = flagWS;

    // 4-dispatch pipeline: hat_prep -> fused(it0) -> fused(it1) -> red2
    fused_iter<<<1024, 256, 0, stream>>>(ma, syncWS + 0,  syncWS + 20, 0);
    fused_iter<<<1024, 256, 0, stream>>>(ma, syncWS + 64, syncWS + 84, 1);
    red_pass256<<<NROWS, 256, 0, stream>>>(ma, 2);
}

// Round 7
// 188.996 us; speedup vs baseline: 2.7870x; 2.7870x over previous
//
#include <hip/hip_runtime.h>
#include <math.h>

// Problem constants
#define BATCH  128
#define NIN    1152
#define DIN    8
#define NOUTC  10
#define DOUT   16
#define H1DIM  512
#define H2DIM  1024
#define PIX    784
#define NROWS  (BATCH * NOUTC)   // 1280
#define GN     32                // gemm N-tile
#define PARTS  25                // ceil(784/GN) col-tiles in gemm3
#define PSTR   32                // partials row stride

typedef __attribute__((ext_vector_type(8))) __bf16 bf16x8;
typedef __attribute__((ext_vector_type(4))) float  f32x4;
typedef __attribute__((ext_vector_type(4))) unsigned int u32x4;

__device__ __forceinline__ float bf2f(unsigned int u) {
    union { unsigned int i; float f; } v; v.i = u << 16; return v.f;
}
__device__ __forceinline__ ushort f2bf(float f) {
    union { float f; unsigned int i; } v; v.f = f;
    unsigned int r = v.i + 0x7FFFu + ((v.i >> 16) & 1u);
    return (ushort)(r >> 16);
}
__device__ __forceinline__ float ldin(const void* p, size_t i, int isbf) {
    return isbf ? bf2f(((const ushort*)p)[i]) : ((const float*)p)[i];
}
__device__ __forceinline__ bf16x8 frag_of(uint4 u) {
    return __builtin_bit_cast(bf16x8, u);
}
__device__ __forceinline__ bf16x8 ld_frag(const ushort* p) {
    return frag_of(*(const uint4*)p);
}
// unpack a uint4 of 8 bf16 into 8 f32
__device__ __forceinline__ void unpack8(uint4 u, float* f) {
    f[0] = bf2f(u.x & 0xffffu); f[1] = bf2f(u.x >> 16);
    f[2] = bf2f(u.y & 0xffffu); f[3] = bf2f(u.y >> 16);
    f[4] = bf2f(u.z & 0xffffu); f[5] = bf2f(u.z >> 16);
    f[6] = bf2f(u.w & 0xffffu); f[7] = bf2f(u.w >> 16);
}

// per-block dtype detect: 1 KB of w, same answer in every block
__device__ __forceinline__ int detect_bf(const void* w, int* cntS) {
    int tid = threadIdx.x, nt = blockDim.x;
    if (tid == 0) *cntS = 0;
    __syncthreads();
    const ushort* u = (const ushort*)w;
    int c = 0;
    for (int s = tid; s < 512; s += nt) {
        int e = (u[s * 2] >> 7) & 0xFF;
        if (e >= 88 && e <= 140) c++;
    }
    atomicAdd(cntS, c);
    __syncthreads();
    return (*cntS >= 384) ? 1 : 0;
}

// ---------------------------------------------------------------------------
// prep args. segments: 0:W1 1:b1 2:b2 3:b3 4:x 5:W2^T 6:W3^T.
// ---------------------------------------------------------------------------
struct PrepArgs {
    const void* w;
    const void* src[7];
    ushort*     dst[7];
    int         n[7];
    int*        flag;
};

// fallback-only (ws too small for hatG): original standalone prep
__global__ __launch_bounds__(256) void prep_kernel(PrepArgs a)
{
    __shared__ int cntS;
    __shared__ ushort tile[32][33];
    int tid = threadIdx.x;
    int isbf = detect_bf(a.w, &cntS);
    int seg = blockIdx.y;
    if (seg == 0 && blockIdx.x == 0 && tid == 0) *a.flag = isbf;

    if (seg <= 4) {
        int n = a.n[seg];
        int stride = gridDim.x * 256;
        ushort* d = a.dst[seg];
        if (isbf) {
            const ushort* s = (const ushort*)a.src[seg];
            for (int i = blockIdx.x * 256 + tid; i < n; i += stride) d[i] = s[i];
        } else {
            const float* s = (const float*)a.src[seg];
            for (int i = blockIdx.x * 256 + tid; i < n; i += stride) d[i] = f2bf(s[i]);
        }
        return;
    }
    int R = (seg == 5) ? H1DIM : H2DIM;
    int C = (seg == 5) ? H2DIM : PIX;
    int tilesX = (seg == 5) ? 32 : 25;
    int tilesY = (seg == 5) ? 16 : 32;
    int t = blockIdx.x;
    if (t >= tilesX * tilesY) return;
    int tx2 = t % tilesX, ty2 = t / tilesX;
    int c0 = tx2 * 32, r0 = ty2 * 32;
    const void* in = a.src[seg];
    ushort* out = a.dst[seg];
    int tx = tid & 31, ty = tid >> 5;
    for (int i = ty; i < 32; i += 8) {
        int r = r0 + i, c = c0 + tx;
        tile[i][tx] = (r < R && c < C) ? f2bf(ldin(in, (size_t)r * C + c, isbf)) : (ushort)0;
    }
    __syncthreads();
    for (int i = ty; i < 32; i += 8) {
        int c = c0 + i, r = r0 + tx;
        if (c < C && r < R) out[(size_t)c * R + r] = tile[tx][i];
    }
}

// ---------------------------------------------------------------------------
// hat_prep_kernel: merged hat_build + prep (round-2 structure, verified).
//   z < NOUTC  : hat[b,n,k,o]; all loads issued in a register prologue
//                before any store (in-order vmcnt retirement).
//   z >= NOUTC : 576 prep blocks (528 transpose tiles + 48 copy blocks).
// ---------------------------------------------------------------------------
__global__ __launch_bounds__(256) void hat_prep_kernel(
    const void* __restrict__ inc,
    PrepArgs a,
    ushort* __restrict__ hatG)
{
    __shared__ int cntS;
    __shared__ ushort tile[32][33];
    int tid = threadIdx.x;
    int isbf = detect_bf(a.w, &cntS);

    if (blockIdx.z >= NOUTC) {
        int p = (blockIdx.z - NOUTC) * 144 + blockIdx.y * 9 + blockIdx.x;  // 0..575
        if (p == 0 && tid == 0) *a.flag = isbf;
        if (p < 528) {
            for (int t = p; t < 1312; t += 528) {
                int seg = (t < 512) ? 5 : 6;
                int tt  = (seg == 5) ? t : t - 512;
                int R = (seg == 5) ? H1DIM : H2DIM;
                int C = (seg == 5) ? H2DIM : PIX;
                int tilesX = (seg == 5) ? 32 : 25;
                int tx2 = tt % tilesX, ty2 = tt / tilesX;
                int c0 = tx2 * 32, r0 = ty2 * 32;
                const void* in = a.src[seg];
                ushort* out = a.dst[seg];
                int tx = tid & 31, ty = tid >> 5;
                for (int i = ty; i < 32; i += 8) {
                    int r = r0 + i, c = c0 + tx;
                    tile[i][tx] = (r < R && c < C) ? f2bf(ldin(in, (size_t)r * C + c, isbf)) : (ushort)0;
                }
                __syncthreads();
                for (int i = ty; i < 32; i += 8) {
                    int c = c0 + i, r = r0 + tx;
                    if (c < C && r < R) out[(size_t)c * R + r] = tile[tx][i];
                }
                __syncthreads();
            }
        } else {
            int base = (p - 528) * 256 + tid;
            const int stride = 48 * 256;
            #pragma unroll
            for (int seg = 0; seg <= 4; seg++) {
                int n = a.n[seg];
                ushort* d = a.dst[seg];
                if (isbf) {
                    const ushort* s = (const ushort*)a.src[seg];
                    for (int i = base; i < n; i += stride) d[i] = s[i];
                } else {
                    const float* s = (const float*)a.src[seg];
                    for (int i = base; i < n; i += stride) d[i] = f2bf(s[i]);
                }
            }
        }
        return;
    }

    // -------- hat path: 8 batches per block, all loads in prologue --------
    int kc = blockIdx.x, bc = blockIdx.y, n = blockIdx.z;
    int k  = kc * 128 + (tid >> 1);
    int oh = (tid & 1) << 3;
    int b0 = bc * 8;

    size_t wbase = ((size_t)n * NIN + k) * DOUT + oh;

    if (isbf) {
        uint4 wr[8], ir[8];
        const uint4* wp = (const uint4*)((const ushort*)a.w + wbase * DIN);
        const ushort* ip = (const ushort*)inc;
        #pragma unroll
        for (int j = 0; j < 8; j++) wr[j] = wp[j];
        #pragma unroll
        for (int bl = 0; bl < 8; bl++)
            ir[bl] = *(const uint4*)(ip + ((size_t)(b0 + bl) * NIN + k) * DIN);
        float wf[8][8];
        #pragma unroll
        for (int j = 0; j < 8; j++) unpack8(wr[j], wf[j]);
        #pragma unroll
        for (int bl = 0; bl < 8; bl++) {
            float xi[8];
            unpack8(ir[bl], xi);
            unsigned int hh[8];
            #pragma unroll
            for (int j = 0; j < 8; j++) {
                float s = wf[j][0] * xi[0] + wf[j][1] * xi[1] + wf[j][2] * xi[2] +
                          wf[j][3] * xi[3] + wf[j][4] * xi[4] + wf[j][5] * xi[5] +
                          wf[j][6] * xi[6] + wf[j][7] * xi[7];
                hh[j] = f2bf(s);
            }
            u32x4 ov = { hh[0] | (hh[1] << 16), hh[2] | (hh[3] << 16),
                         hh[4] | (hh[5] << 16), hh[6] | (hh[7] << 16) };
            *(u32x4*)(hatG + (((size_t)((b0 + bl) * NOUTC + n) * NIN + k) * DOUT + oh)) = ov;
        }
    } else {
        float4 wlo[8], whi[8], ilo[8], ihi[8];
        const float4* wp = (const float4*)((const float*)a.w + wbase * DIN);
        const float*  ip = (const float*)inc;
        #pragma unroll
        for (int j = 0; j < 8; j++) { wlo[j] = wp[2 * j]; whi[j] = wp[2 * j + 1]; }
        #pragma unroll
        for (int bl = 0; bl < 8; bl++) {
            const float4* q = (const float4*)(ip + ((size_t)(b0 + bl) * NIN + k) * DIN);
            ilo[bl] = q[0]; ihi[bl] = q[1];
        }
        #pragma unroll
        for (int bl = 0; bl < 8; bl++) {
            float4 lo = ilo[bl], hi = ihi[bl];
            unsigned int hh[8];
            #pragma unroll
            for (int j = 0; j < 8; j++) {
                float s = wlo[j].x * lo.x + wlo[j].y * lo.y + wlo[j].z * lo.z +
                          wlo[j].w * lo.w + whi[j].x * hi.x + whi[j].y * hi.y +
                          whi[j].z * hi.z + whi[j].w * hi.w;
                hh[j] = f2bf(s);
            }
            u32x4 ov = { hh[0] | (hh[1] << 16), hh[2] | (hh[3] << 16),
                         hh[4] | (hh[5] << 16), hh[6] | (hh[7] << 16) };
            *(u32x4*)(hatG + (((size_t)((b0 + bl) * NOUTC + n) * NIN + k) * DOUT + oh)) = ov;
        }
    }
}

// ---------------------------------------------------------------------------
// reduce_hat512: round-2's verified 512-thread reduce (hat from hatG in
// registers, rows 1024..1151 via 4 KB LDS tail). Partials: 25 tiles, stride 32.
// ---------------------------------------------------------------------------
__global__ __launch_bounds__(512, 4) void reduce_hat512(
    const ushort* __restrict__ hatG,
    const ushort* __restrict__ bsPrev,
    const float*  __restrict__ partials,   // (NROWS, PSTR)
    int iter0,
    const ushort* __restrict__ W1c,
    const ushort* __restrict__ b1c,
    ushort* __restrict__ h1out,
    ushort* __restrict__ bsOut,
    void*   __restrict__ outFinal,
    const int* __restrict__ flagp)
{
    int bn  = blockIdx.x;
    int n   = bn % NOUTC;
    int b   = bn / NOUTC;
    int tid = threadIdx.x;

    __shared__ ushort wSb[NIN];               // 2.3 KB
    __shared__ float  redS[8][16];
    __shared__ float  sumS[16];
    __shared__ float  ocS[16];
    __shared__ float  scaleS;
    __shared__ uint4  hatTail4[256];          // 4 KB (rows 1024..1151)

    int h = tid & 1, kb = tid >> 1;           // kb in [0,256)
    int wave = tid >> 6, lane = tid & 63;

    const ushort* hbase = hatG + (size_t)bn * NIN * DOUT;
    uint4 v[4];
    #pragma unroll
    for (int j = 0; j < 4; j++)
        v[j] = *(const uint4*)(hbase + ((kb + 256 * j) * DOUT + h * 8));
    if (tid < 256)
        hatTail4[tid] = *(const uint4*)(hbase + 1024 * DOUT + tid * 8);
    const ushort* tailS = (const ushort*)hatTail4;

    if (!iter0) {
        if (tid < 9) {
            float s = 0.f;
            #pragma unroll
            for (int j = 0; j < PARTS; j++)
                s += partials[(size_t)(b * NOUTC + tid) * PSTR + j];
            sumS[tid] = -s;
        }
        __syncthreads();
        float mn = 1e30f, mx = -1e30f;
        #pragma unroll
        for (int n2 = 0; n2 < 9; n2++) {
            float vv = sumS[n2];
            mn = fminf(mn, vv); mx = fmaxf(mx, vv);
        }
        float den = fmaxf(mx - mn, 1e-6f);
        float rv = (n < 9) ? fmaxf((sumS[n] - mn) / den, 0.5f) : 0.5f;
        for (int k = tid; k < NIN; k += 512) {
            float c = 0.5f;
            if (n < 9) {
                float vv[9], mn2 = 1e30f, mx2 = -1e30f;
                #pragma unroll
                for (int n2 = 0; n2 < 9; n2++) {
                    vv[n2] = bf2f(bsPrev[(size_t)(b * NOUTC + n2) * NIN + k]);
                    mn2 = fminf(mn2, vv[n2]); mx2 = fmaxf(mx2, vv[n2]);
                }
                float den2 = fmaxf(mx2 - mn2, 1e-6f);
                c = fmaxf((vv[n] - mn2) / den2, 0.5f);
            }
            wSb[k] = f2bf(c * rv);
        }
    }
    __syncthreads();

    // weighted k-sum from registers (+ LDS tail)
    float acc[8];
    #pragma unroll
    for (int o = 0; o < 8; o++) acc[o] = 0.f;
    #pragma unroll
    for (int j = 0; j < 4; j++) {
        int k = kb + 256 * j;
        float w = iter0 ? 1.f : bf2f(wSb[k]);
        bf16x8 hv = frag_of(v[j]);
        #pragma unroll
        for (int o = 0; o < 8; o++) acc[o] += w * (float)hv[o];
    }
    if (tid < 256) {                          // tail rows 1024..1151
        int k = 1024 + kb;
        float w = iter0 ? 1.f : bf2f(wSb[k]);
        bf16x8 hv = ld_frag(tailS + kb * DOUT + h * 8);
        #pragma unroll
        for (int o = 0; o < 8; o++) acc[o] += w * (float)hv[o];
    }
    #pragma unroll
    for (int off = 32; off >= 2; off >>= 1) {
        #pragma unroll
        for (int o = 0; o < 8; o++) acc[o] += __shfl_xor(acc[o], off);
    }
    if (lane < 2) {
        #pragma unroll
        for (int o = 0; o < 8; o++) redS[wave][lane * 8 + o] = acc[o];
    }
    __syncthreads();
    if (tid < 16) {
        float s = 0.f;
        #pragma unroll
        for (int wv = 0; wv < 8; wv++) s += redS[wv][tid];
        sumS[tid] = s;
    }
    __syncthreads();
    if (tid == 0) {
        float n2 = 0.f;
        #pragma unroll
        for (int o = 0; o < 16; o++) n2 += sumS[o] * sumS[o];
        float nrm = sqrtf(n2);
        scaleS = n2 / (1.f + n2) / (nrm + 1e-8f);
    }
    __syncthreads();
    if (tid < 16) {
        float oc = scaleS * sumS[tid];
        ocS[tid] = oc;
        if (outFinal) {
            if (*flagp) ((ushort*)outFinal)[(size_t)bn * 16 + tid] = f2bf(oc);
            else        ((float*) outFinal)[(size_t)bn * 16 + tid] = oc;
        }
    }
    __syncthreads();

    // bscore from registers (+ LDS tail)
    if (bsOut) {
        float o0 = ocS[h * 8 + 0], o1 = ocS[h * 8 + 1], o2 = ocS[h * 8 + 2],
              o3 = ocS[h * 8 + 3], o4 = ocS[h * 8 + 4], o5 = ocS[h * 8 + 5],
              o6 = ocS[h * 8 + 6], o7 = ocS[h * 8 + 7];
        #pragma unroll
        for (int j = 0; j < 4; j++) {
            bf16x8 hv = frag_of(v[j]);
            float s = o0 * (float)hv[0] + o1 * (float)hv[1] + o2 * (float)hv[2] +
                      o3 * (float)hv[3] + o4 * (float)hv[4] + o5 * (float)hv[5] +
                      o6 * (float)hv[6] + o7 * (float)hv[7];
            s += __shfl_xor(s, 1);
            if (h == 0) bsOut[(size_t)bn * NIN + kb + 256 * j] = f2bf(s);
        }
        if (tid < 256) {
            bf16x8 hv = ld_frag(tailS + kb * DOUT + h * 8);
            float s = o0 * (float)hv[0] + o1 * (float)hv[1] + o2 * (float)hv[2] +
                      o3 * (float)hv[3] + o4 * (float)hv[4] + o5 * (float)hv[5] +
                      o6 * (float)hv[6] + o7 * (float)hv[7];
            s += __shfl_xor(s, 1);
            if (h == 0) bsOut[(size_t)bn * NIN + 1024 + kb] = f2bf(s);
        }
    }

    // fused decoder layer 1 (block-diagonal): one column per thread
    if (h1out) {
        int col = tid;
        float acc1 = bf2f(b1c[col]);
        #pragma unroll
        for (int i = 0; i < 16; i++)
            acc1 += ocS[i] * bf2f(W1c[(size_t)(n * 16 + i) * H1DIM + col]);
        h1out[(size_t)bn * H1DIM + col] = f2bf(fmaxf(acc1, 0.f));
    }
}

// ---------------------------------------------------------------------------
// 64x32-tile MFMA GEMM (was 64x64): doubles block count -> ~2.5 blocks/CU for
// latency hiding (old 320/260 blocks = ~1/CU exposed every k-stage barrier).
// 64-wide k-stages; LDS rows padded to 40 ushorts (conflict-free b128 reads).
// ---------------------------------------------------------------------------
__global__ __launch_bounds__(256) void gemm_kernel(
    const ushort* __restrict__ A, const ushort* __restrict__ Bt,
    const ushort* __restrict__ bias, int K, int N,
    ushort* __restrict__ Cout,
    const ushort* __restrict__ xin, float* __restrict__ partials)
{
    int m0 = blockIdx.x * 64, n0 = blockIdx.y * GN;
    int tid = threadIdx.x;
    int wave = tid >> 6, lane = tid & 63, quad = lane >> 4, l16 = lane & 15;

    __shared__ uint4 As4[640];                // 2 chunks x 320 (64 rows x 5)
    __shared__ uint4 Bs4[320];                // 2 chunks x 160 (32 rows x 5)
    ushort* As = (ushort*)As4;
    ushort* Bs = (ushort*)Bs4;

    f32x4 acc[2];
    #pragma unroll
    for (int nt = 0; nt < 2; nt++)
        #pragma unroll
        for (int rg = 0; rg < 4; rg++) acc[nt][rg] = 0.f;

    // A staging: 64 rows x 32k per chunk, one uint4/thread/chunk
    int sMi = tid >> 2, sKk = (tid & 3) * 8;
    int sLds = sMi * 5 + (tid & 3);
    const ushort* Ap = A + (size_t)(m0 + sMi) * K + sKk;
    // B staging: 32 rows x 64k, one uint4/thread total (thread>>7 picks chunk)
    int bMi = (tid & 127) >> 2, bChunk = tid >> 7;
    int bLds = bChunk * 160 + bMi * 5 + (tid & 3);
    const ushort* Bp = Bt + (size_t)(n0 + bMi) * K + sKk + bChunk * 32;
    bool bOK = (n0 + bMi) < N;

    uint4 aR0 = *(const uint4*)Ap;
    uint4 aR1 = *(const uint4*)(Ap + 32);
    uint4 bR  = bOK ? *(const uint4*)Bp : make_uint4(0, 0, 0, 0);

    for (int k0 = 0; k0 < K; k0 += 64) {
        As4[sLds]       = aR0;
        As4[320 + sLds] = aR1;
        Bs4[bLds]       = bR;
        __syncthreads();
        if (k0 + 64 < K) {
            aR0 = *(const uint4*)(Ap + k0 + 64);
            aR1 = *(const uint4*)(Ap + k0 + 96);
            bR  = bOK ? *(const uint4*)(Bp + k0 + 64) : make_uint4(0, 0, 0, 0);
        }
        #pragma unroll
        for (int c = 0; c < 2; c++) {
            bf16x8 a = ld_frag(As + c * 2560 + (wave * 16 + l16) * 40 + quad * 8);
            #pragma unroll
            for (int nt = 0; nt < 2; nt++) {
                bf16x8 bb = ld_frag(Bs + c * 1280 + (nt * 16 + l16) * 40 + quad * 8);
                acc[nt] = __builtin_amdgcn_mfma_f32_16x16x32_bf16(a, bb, acc[nt], 0, 0, 0);
            }
        }
        __syncthreads();
    }

    int rowBase = m0 + wave * 16 + quad * 4;
    if (Cout) {
        #pragma unroll
        for (int nt = 0; nt < 2; nt++) {
            int col = n0 + nt * 16 + l16;
            float bv = bf2f(bias[col]);
            #pragma unroll
            for (int rg = 0; rg < 4; rg++) {
                float v = acc[nt][rg] + bv;
                Cout[(size_t)(rowBase + rg) * N + col] = f2bf(fmaxf(v, 0.f));
            }
        }
    } else {
        float vr[4] = {0.f, 0.f, 0.f, 0.f};
        #pragma unroll
        for (int nt = 0; nt < 2; nt++) {
            int col = n0 + nt * 16 + l16;
            if (col < N) {
                float bv = bf2f(bias[col]);
                #pragma unroll
                for (int rg = 0; rg < 4; rg++) {
                    int row = rowBase + rg;
                    int bb = row / NOUTC;
                    float z = acc[nt][rg] + bv;
                    float s = 1.f / (1.f + __expf(-z));
                    float d = bf2f(xin[(size_t)bb * PIX + col]) - s;
                    vr[rg] += d * d;
                }
            }
        }
        #pragma unroll
        for (int rg = 0; rg < 4; rg++) {
            float v = vr[rg];
            #pragma unroll
            for (int off = 8; off >= 1; off >>= 1) v += __shfl_xor(v, off, 16);
            if (l16 == 0)
                partials[(size_t)(rowBase + rg) * PSTR + blockIdx.y] = v;
        }
    }
}

// ---------------------------------------------------------------------------
// Fallback path (ws too small for hatG): 512-thread compute-reduce
// ---------------------------------------------------------------------------
__global__ __launch_bounds__(512, 4) void reduce_compute(
    const void*   __restrict__ incRaw,
    const void*   __restrict__ wRaw,
    const ushort* __restrict__ bsPrev,
    const float*  __restrict__ partials,
    int iter0,
    const ushort* __restrict__ W1c,
    const ushort* __restrict__ b1c,
    ushort* __restrict__ h1out,
    ushort* __restrict__ bsOut,
    void*   __restrict__ outFinal,
    const int* __restrict__ flagp)
{
    int bn  = blockIdx.x;
    int n   = bn % NOUTC;
    int b   = bn / NOUTC;
    int tid = threadIdx.x;

    __shared__ ushort wSb[NIN];
    __shared__ float  redS[8][16];
    __shared__ float  sumS[16];
    __shared__ float  ocS[16];
    __shared__ float  scaleS;

    int h = tid & 1, kb = tid >> 1;
    int wave = tid >> 6, lane = tid & 63;

    uint4 v[4];
    const ushort* tailS;

    __shared__ int cntS;
    __shared__ uint4 hatS4[NIN * DOUT / 8];
    int isbf = detect_bf(wRaw, &cntS);
    size_t wnb = (size_t)n * NIN * DOUT * DIN;
    for (int idx = tid; idx < NIN * DOUT; idx += 512) {
        int k = idx >> 4;
        float s = 0.f;
        #pragma unroll
        for (int i = 0; i < 8; i++)
            s += ldin(wRaw, wnb + (size_t)idx * 8 + i, isbf) *
                 ldin(incRaw, ((size_t)b * NIN + k) * DIN + i, isbf);
        ((ushort*)hatS4)[idx] = f2bf(s);
    }
    __syncthreads();
    const ushort* hbase = (const ushort*)hatS4;
    #pragma unroll
    for (int j = 0; j < 4; j++)
        v[j] = *(const uint4*)(hbase + ((kb + 256 * j) * DOUT + h * 8));
    tailS = hbase + 1024 * DOUT;

    if (!iter0) {
        if (tid < 9) {
            float s = 0.f;
            #pragma unroll
            for (int j = 0; j < PARTS; j++)
                s += partials[(size_t)(b * NOUTC + tid) * PSTR + j];
            sumS[tid] = -s;
        }
        __syncthreads();
        float mn = 1e30f, mx = -1e30f;
        #pragma unroll
        for (int n2 = 0; n2 < 9; n2++) {
            float vv = sumS[n2];
            mn = fminf(mn, vv); mx = fmaxf(mx, vv);
        }
        float den = fmaxf(mx - mn, 1e-6f);
        float rv = (n < 9) ? fmaxf((sumS[n] - mn) / den, 0.5f) : 0.5f;
        for (int k = tid; k < NIN; k += 512) {
            float c = 0.5f;
            if (n < 9) {
                float vv[9], mn2 = 1e30f, mx2 = -1e30f;
                #pragma unroll
                for (int n2 = 0; n2 < 9; n2++) {
                    vv[n2] = bf2f(bsPrev[(size_t)(b * NOUTC + n2) * NIN + k]);
                    mn2 = fminf(mn2, vv[n2]); mx2 = fmaxf(mx2, vv[n2]);
                }
                float den2 = fmaxf(mx2 - mn2, 1e-6f);
                c = fmaxf((vv[n] - mn2) / den2, 0.5f);
            }
            wSb[k] = f2bf(c * rv);
        }
    }
    __syncthreads();

    float acc[8];
    #pragma unroll
    for (int o = 0; o < 8; o++) acc[o] = 0.f;
    #pragma unroll
    for (int j = 0; j < 4; j++) {
        int k = kb + 256 * j;
        float w = iter0 ? 1.f : bf2f(wSb[k]);
        bf16x8 hv = frag_of(v[j]);
        #pragma unroll
        for (int o = 0; o < 8; o++) acc[o] += w * (float)hv[o];
    }
    if (tid < 256) {
        int k = 1024 + kb;
        float w = iter0 ? 1.f : bf2f(wSb[k]);
        bf16x8 hv = ld_frag(tailS + kb * DOUT + h * 8);
        #pragma unroll
        for (int o = 0; o < 8; o++) acc[o] += w * (float)hv[o];
    }
    #pragma unroll
    for (int off = 32; off >= 2; off >>= 1) {
        #pragma unroll
        for (int o = 0; o < 8; o++) acc[o] += __shfl_xor(acc[o], off);
    }
    if (lane < 2) {
        #pragma unroll
        for (int o = 0; o < 8; o++) redS[wave][lane * 8 + o] = acc[o];
    }
    __syncthreads();
    if (tid < 16) {
        float s = 0.f;
        #pragma unroll
        for (int wv = 0; wv < 8; wv++) s += redS[wv][tid];
        sumS[tid] = s;
    }
    __syncthreads();
    if (tid == 0) {
        float n2 = 0.f;
        #pragma unroll
        for (int o = 0; o < 16; o++) n2 += sumS[o] * sumS[o];
        float nrm = sqrtf(n2);
        scaleS = n2 / (1.f + n2) / (nrm + 1e-8f);
    }
    __syncthreads();
    if (tid < 16) {
        float oc = scaleS * sumS[tid];
        ocS[tid] = oc;
        if (outFinal) {
            if (*flagp) ((ushort*)outFinal)[(size_t)bn * 16 + tid] = f2bf(oc);
            else        ((float*) outFinal)[(size_t)bn * 16 + tid] = oc;
        }
    }
    __syncthreads();

    if (bsOut) {
        float o0 = ocS[h * 8 + 0], o1 = ocS[h * 8 + 1], o2 = ocS[h * 8 + 2],
              o3 = ocS[h * 8 + 3], o4 = ocS[h * 8 + 4], o5 = ocS[h * 8 + 5],
              o6 = ocS[h * 8 + 6], o7 = ocS[h * 8 + 7];
        #pragma unroll
        for (int j = 0; j < 4; j++) {
            bf16x8 hv = frag_of(v[j]);
            float s = o0 * (float)hv[0] + o1 * (float)hv[1] + o2 * (float)hv[2] +
                      o3 * (float)hv[3] + o4 * (float)hv[4] + o5 * (float)hv[5] +
                      o6 * (float)hv[6] + o7 * (float)hv[7];
            s += __shfl_xor(s, 1);
            if (h == 0) bsOut[(size_t)bn * NIN + kb + 256 * j] = f2bf(s);
        }
        if (tid < 256) {
            bf16x8 hv = ld_frag(tailS + kb * DOUT + h * 8);
            float s = o0 * (float)hv[0] + o1 * (float)hv[1] + o2 * (float)hv[2] +
                      o3 * (float)hv[3] + o4 * (float)hv[4] + o5 * (float)hv[5] +
                      o6 * (float)hv[6] + o7 * (float)hv[7];
            s += __shfl_xor(s, 1);
            if (h == 0) bsOut[(size_t)bn * NIN + 1024 + kb] = f2bf(s);
        }
    }

    if (h1out) {
        int col = tid;
        float acc1 = bf2f(b1c[col]);
        #pragma unroll
        for (int i = 0; i < 16; i++)
            acc1 += ocS[i] * bf2f(W1c[(size_t)(n * 16 + i) * H1DIM + col]);
        h1out[(size_t)bn * H1DIM + col] = f2bf(fmaxf(acc1, 0.f));
    }
}

// ---------------------------------------------------------------------------
extern "C" void kernel_launch(void* const* d_in, const int* in_sizes, int n_in,
                              void* d_out, int out_size, void* d_ws, size_t ws_size,
                              hipStream_t stream)
{
    const void* inc = d_in[0];
    const void* x   = d_in[1];
    const void* w   = d_in[2];
    const void* W1  = d_in[3];
    const void* b1  = d_in[4];
    const void* W2  = d_in[5];
    const void* b2  = d_in[6];
    const void* W3  = d_in[7];
    const void* b3  = d_in[8];

    char* p = (char*)d_ws;
    auto alloc = [&](size_t bytes) { void* r = p; p += (bytes + 255) & ~(size_t)255; return r; };
    int*    flagWS    = (int*)alloc(256);
    ushort* bsA       = (ushort*)alloc((size_t)NROWS * NIN * 2);
    ushort* bsB       = (ushort*)alloc((size_t)NROWS * NIN * 2);
    float*  partials  = (float*)alloc((size_t)NROWS * PSTR * 4);
    ushort* h1WS      = (ushort*)alloc((size_t)NROWS * H1DIM * 2);
    ushort* h2WS      = (ushort*)alloc((size_t)NROWS * H2DIM * 2);
    ushort* W2T       = (ushort*)alloc((size_t)H2DIM * H1DIM * 2);
    ushort* W3T       = (ushort*)alloc((size_t)PIX * H2DIM * 2);
    ushort* W1c       = (ushort*)alloc((size_t)160 * H1DIM * 2);
    ushort* b1c       = (ushort*)alloc((size_t)H1DIM * 2);
    ushort* b2c       = (ushort*)alloc((size_t)H2DIM * 2);
    ushort* b3c       = (ushort*)alloc((size_t)PIX * 2);
    ushort* xc        = (ushort*)alloc((size_t)BATCH * PIX * 2);
    ushort* hatG      = (ushort*)alloc((size_t)NROWS * NIN * DOUT * 2);  // 47 MB, LAST
    bool haveHat = ((char*)hatG + (size_t)NROWS * NIN * DOUT * 2) <= ((char*)d_ws + ws_size);

    PrepArgs pa;
    pa.w = w;
    pa.src[0] = W1;  pa.dst[0] = W1c;  pa.n[0] = 160 * H1DIM;
    pa.src[1] = b1;  pa.dst[1] = b1c;  pa.n[1] = H1DIM;
    pa.src[2] = b2;  pa.dst[2] = b2c;  pa.n[2] = H2DIM;
    pa.src[3] = b3;  pa.dst[3] = b3c;  pa.n[3] = PIX;
    pa.src[4] = x;   pa.dst[4] = xc;   pa.n[4] = BATCH * PIX;
    pa.src[5] = W2;  pa.dst[5] = W2T;  pa.n[5] = 0;
    pa.src[6] = W3;  pa.dst[6] = W3T;  pa.n[6] = 0;
    pa.flag = flagWS;

    if (!haveHat) {
        // ws too small: separated compute path
        prep_kernel<<<dim3(800, 7), 256, 0, stream>>>(pa);
        reduce_compute<<<NROWS, 512, 0, stream>>>(
            inc, w, nullptr, nullptr, 1, W1c, b1c, h1WS, bsA, nullptr, flagWS);
        for (int it = 0; it < 2; it++) {
            gemm_kernel<<<dim3(NROWS / 64, H2DIM / GN), 256, 0, stream>>>(
                h1WS, W2T, b2c, H1DIM, H2DIM, h2WS, nullptr, nullptr);
            gemm_kernel<<<dim3(NROWS / 64, PARTS), 256, 0, stream>>>(
                h2WS, W3T, b3c, H2DIM, PIX, nullptr, xc, partials);
            int last = (it == 1);
            const ushort* bsP = (it == 0) ? bsA : bsB;
            ushort* bsO       = last ? nullptr : bsB;
            ushort* h1o       = last ? nullptr : h1WS;
            void*   fin       = last ? d_out : nullptr;
            reduce_compute<<<NROWS, 512, 0, stream>>>(
                inc, w, bsP, partials, 0, W1c, b1c, h1o, bsO, fin, flagWS);
        }
        return;
    }

    hat_prep_kernel<<<dim3(9, 16, NOUTC + 4), 256, 0, stream>>>(inc, pa, hatG);

    reduce_hat512<<<NROWS, 512, 0, stream>>>(
        hatG, nullptr, nullptr, 1, W1c, b1c, h1WS, bsA, nullptr, flagWS);

    for (int it = 0; it < 2; it++) {
        gemm_kernel<<<dim3(NROWS / 64, H2DIM / GN), 256, 0, stream>>>(
            h1WS, W2T, b2c, H1DIM, H2DIM, h2WS, nullptr, nullptr);
        gemm_kernel<<<dim3(NROWS / 64, PARTS), 256, 0, stream>>>(
            h2WS, W3T, b3c, H2DIM, PIX, nullptr, xc, partials);

        int last = (it == 1);
        const ushort* bsP = (it == 0) ? bsA : bsB;
        ushort* bsO       = last ? nullptr : bsB;
        ushort* h1o       = last ? nullptr : h1WS;
        void*   fin       = last ? d_out : nullptr;
        reduce_hat512<<<NROWS, 512, 0, stream>>>(
            hatG, bsP, partials, 0, W1c, b1c, h1o, bsO, fin, flagWS);
    }
}